// Round 15
// baseline (167.065 us; speedup 1.0000x reference)
//
#include <hip/hip_runtime.h>

typedef __bf16 bf16x8 __attribute__((ext_vector_type(8)));
typedef float f32x4 __attribute__((ext_vector_type(4)));
typedef unsigned short ushort8v __attribute__((ext_vector_type(8)));
typedef unsigned short ushort4v __attribute__((ext_vector_type(4)));

#define BATCH 32
#define NBOX 40
#define CCH 256
#define HF 64
#define WF 64
#define RREG 29
#define OUTP 7
#define MROWS 928           // BATCH*RREG
#define DDIM 12544          // CCH*7*7
#define N1DIM 2048
#define FDIM 768
#define PDIM 4096           // HF*WF
#define S1 8                // split-K GEMM1 (25/.../21 K-tiles per split)
#define S2 8                // split-K factor GEMM2

// ---- workspace layout (bytes). Gp is bf16 [S][rows][cols]. ----
static constexpr size_t OFF_ROIS = 0;                                   // 928*4 f32
static constexpr size_t OFF_DET  = 16384;                               // 928 i32
static constexpr size_t OFF_A    = 32768;                               // bf16 [928][12544]
static constexpr size_t OFF_W1T  = OFF_A   + (size_t)MROWS * DDIM * 2;  // bf16 [2048][12544]
static constexpr size_t OFF_W2T  = OFF_W1T + (size_t)DDIM * N1DIM * 2;  // bf16 [768][2048]
static constexpr size_t OFF_GP   = OFF_W2T + (size_t)N1DIM * FDIM * 2;  // bf16 [S1][928][2048] / [S2][928][768]
static constexpr size_t OFF_FMT  = OFF_GP  + (size_t)S1 * MROWS * N1DIM * 2; // bf16 [32][4096][256]
static constexpr size_t OFF_H    = OFF_W1T;                             // bf16 [928][2048] (W1T dead after gemm1)

static __device__ __forceinline__ unsigned short f2bf(float f) {
  __bf16 h = (__bf16)f;
  return __builtin_bit_cast(unsigned short, h);
}
static __device__ __forceinline__ float bf2f(unsigned short u) {
  unsigned int x = ((unsigned int)u) << 16;
  return __builtin_bit_cast(float, x);
}
static __device__ __forceinline__ void gload_lds16(const void* g, void* l) {
  __builtin_amdgcn_global_load_lds((const __attribute__((address_space(1))) void*)g,
                                   (__attribute__((address_space(3))) void*)l, 16, 0, 0);
}

// ---------------- 1. select (4 blocks) + fmt NCHW f32 -> NHWC bf16 (8192 blocks) ----
__global__ __launch_bounds__(256) void selfmt_kernel(const float* __restrict__ in,
                                                     unsigned short* __restrict__ out,
                                                     const float* __restrict__ boxes,
                                                     const float* __restrict__ scores,
                                                     const int* __restrict__ labels,
                                                     float* __restrict__ rois,
                                                     int* __restrict__ det,
                                                     float* __restrict__ out_det) {
  __shared__ float tile[64][65];
  int bid = blockIdx.x;
  int t = threadIdx.x;
  if (bid >= PDIM / 64 * (CCH / 64) * BATCH) {   // ---- select part (4 trailing blocks)
    int tid = (bid - PDIM / 64 * (CCH / 64) * BATCH) * 256 + t;
    if (tid >= MROWS) return;
    int b = tid / RREG, r = tid % RREG;
    float bestS = -1.0f;
    int bestN = 0;
    int found = 0;
    for (int n = 0; n < NBOX; ++n) {
      int lab = labels[b * NBOX + n];
      int ri = min(max(lab, 1), RREG) - 1;
      if (ri == r) {
        found = 1;
        float s = scores[b * NBOX + n];
        if (s > bestS) { bestS = s; bestN = n; }
      }
    }
    const float scale = 0.0625f;
    float4 bx = *(const float4*)&boxes[(b * NBOX + bestN) * 4];
    rois[tid * 4 + 0] = bx.x * scale;
    rois[tid * 4 + 1] = bx.y * scale;
    rois[tid * 4 + 2] = bx.z * scale;
    rois[tid * 4 + 3] = bx.w * scale;
    det[tid] = found;
    out_det[tid] = found ? 1.0f : 0.0f;
    return;
  }
  // ---- fmt part
  int p0 = (bid & 63) * 64, c0 = ((bid >> 6) & 3) * 64, b = bid >> 8;
  int tx = t & 15, ty = t >> 4;
#pragma unroll
  for (int q = 0; q < 4; ++q) {
    int r = ty + q * 16;
    float4 v = *(const float4*)&in[((long)b * CCH + c0 + r) * PDIM + p0 + tx * 4];
    tile[r][tx * 4 + 0] = v.x;
    tile[r][tx * 4 + 1] = v.y;
    tile[r][tx * 4 + 2] = v.z;
    tile[r][tx * 4 + 3] = v.w;
  }
  __syncthreads();
#pragma unroll
  for (int q = 0; q < 4; ++q) {
    int r = ty + q * 16;
    ushort4v o;
    o[0] = f2bf(tile[tx * 4 + 0][r]);
    o[1] = f2bf(tile[tx * 4 + 1][r]);
    o[2] = f2bf(tile[tx * 4 + 2][r]);
    o[3] = f2bf(tile[tx * 4 + 3][r]);
    *(ushort4v*)&out[((long)b * PDIM + p0 + r) * CCH + c0 + tx * 4] = o;
  }
}

// ---------------- 2. merged roi-align + weight transpose ----------------
__global__ __launch_bounds__(256) void roiwT_kernel(const unsigned short* __restrict__ fmT,
                                                    const float* __restrict__ rois,
                                                    unsigned short* __restrict__ A,
                                                    const float* __restrict__ w1,
                                                    unsigned short* __restrict__ w1t,
                                                    const float* __restrict__ w2,
                                                    unsigned short* __restrict__ w2t) {
  __shared__ __align__(16) char lds[31360];
  int bid = blockIdx.x;
  int t = threadIdx.x;

  if (bid < MROWS) {
    // ---------------- roi part ----------------
    unsigned short* Arow = (unsigned short*)lds;            // [12544]
    int (*sidx)[4] = (int(*)[4])(lds + 25088);              // [196][4]
    float (*swt)[4] = (float(*)[4])(lds + 28224);           // [196][4]
    int roi = bid;
    float rx1 = rois[roi * 4 + 0], ry1 = rois[roi * 4 + 1];
    float rx2 = rois[roi * 4 + 2], ry2 = rois[roi * 4 + 3];
    float roiw = fmaxf(rx2 - rx1, 1.f), roih = fmaxf(ry2 - ry1, 1.f);
    float bw = roiw * (1.f / OUTP), bh = roih * (1.f / OUTP);
    if (t < 196) {
      int oy = t / 28, rem = t % 28, ox = rem / 4, s = rem % 4, sy = s >> 1, sx = s & 1;
      float y = ry1 + ((float)oy + ((float)sy + 0.5f) * 0.5f) * bh;
      float x = rx1 + ((float)ox + ((float)sx + 0.5f) * 0.5f) * bw;
      bool valid = (y >= -1.f) && (y <= 64.f) && (x >= -1.f) && (x <= 64.f);
      float yc = fminf(fmaxf(y, 0.f), 63.f);
      float xc = fminf(fmaxf(x, 0.f), 63.f);
      int y0 = (int)floorf(yc), x0 = (int)floorf(xc);
      int y1i = min(y0 + 1, 63), x1i = min(x0 + 1, 63);
      float ly = yc - (float)y0, lx = xc - (float)x0;
      float hy = 1.f - ly, hx = 1.f - lx;
      float m = valid ? 1.f : 0.f;
      swt[t][0] = hy * hx * m;
      swt[t][1] = hy * lx * m;
      swt[t][2] = ly * hx * m;
      swt[t][3] = ly * lx * m;
      sidx[t][0] = (y0 * 64 + x0) * CCH;
      sidx[t][1] = (y0 * 64 + x1i) * CCH;
      sidx[t][2] = (y1i * 64 + x0) * CCH;
      sidx[t][3] = (y1i * 64 + x1i) * CCH;
    }
    __syncthreads();
    int b = roi / RREG;
    int cg = t & 63;
    int sub = t >> 6;
    int start = sub * 12 + min(sub, 1);
    int cnt = sub == 0 ? 13 : 12;
    const unsigned short* base = fmT + (long)b * PDIM * CCH + cg * 4;
    for (int bi = 0; bi < cnt; ++bi) {
      int bin = start + bi;
      float a0 = 0.f, a1 = 0.f, a2 = 0.f, a3 = 0.f;
#pragma unroll
      for (int s = 0; s < 4; ++s) {
        int sid = bin * 4 + s;
#pragma unroll
        for (int tp = 0; tp < 4; ++tp) {
          float w = swt[sid][tp];
          ushort4v v = *(const ushort4v*)(base + sidx[sid][tp]);
          a0 += w * bf2f(v[0]);
          a1 += w * bf2f(v[1]);
          a2 += w * bf2f(v[2]);
          a3 += w * bf2f(v[3]);
        }
      }
      Arow[(cg * 4 + 0) * 49 + bin] = f2bf(a0 * 0.25f);
      Arow[(cg * 4 + 1) * 49 + bin] = f2bf(a1 * 0.25f);
      Arow[(cg * 4 + 2) * 49 + bin] = f2bf(a2 * 0.25f);
      Arow[(cg * 4 + 3) * 49 + bin] = f2bf(a3 * 0.25f);
    }
    __syncthreads();
    const ushort8v* src = (const ushort8v*)Arow;
    ushort8v* dst = (ushort8v*)(A + (long)roi * DDIM);
    for (int i = t; i < DDIM / 8; i += 256) dst[i] = src[i];
    return;
  }

  // ---------------- wT part ----------------
  float (*tile)[65] = (float(*)[65])lds;
  int wb = bid - MROWS;
  const float* in;
  unsigned short* out;
  int K, N, k0, n0;
  if (wb < (DDIM / 64) * (N1DIM / 64)) {
    in = w1; out = w1t; K = DDIM; N = N1DIM;
    k0 = (wb % (DDIM / 64)) * 64;
    n0 = (wb / (DDIM / 64)) * 64;
  } else {
    int r = wb - (DDIM / 64) * (N1DIM / 64);
    in = w2; out = w2t; K = N1DIM; N = FDIM;
    k0 = (r % (N1DIM / 64)) * 64;
    n0 = (r / (N1DIM / 64)) * 64;
  }
  int tx = t & 15, ty = t >> 4;
#pragma unroll
  for (int p = 0; p < 4; ++p) {
    int r = ty + p * 16;
    float4 v = *(const float4*)&in[(long)(k0 + r) * N + n0 + tx * 4];
    tile[r][tx * 4 + 0] = v.x;
    tile[r][tx * 4 + 1] = v.y;
    tile[r][tx * 4 + 2] = v.z;
    tile[r][tx * 4 + 3] = v.w;
  }
  __syncthreads();
#pragma unroll
  for (int p = 0; p < 4; ++p) {
    int r = ty + p * 16;
    ushort4v o;
    o[0] = f2bf(tile[tx * 4 + 0][r]);
    o[1] = f2bf(tile[tx * 4 + 1][r]);
    o[2] = f2bf(tile[tx * 4 + 2][r]);
    o[3] = f2bf(tile[tx * 4 + 3][r]);
    *(ushort4v*)&out[(long)(n0 + r) * K + k0 + tx * 4] = o;
  }
}

// ---------------- 4a. GEMM1: 256x256 8-wave counted-vmcnt, snake + ks-split lgkm ----
// Snake order (0,0)->(0,1)->(1,1)->(1,0); A loaded once per mh, B-halves cached.
// NEW: reads issued ks-major; counted lgkmcnt starts the ks=0 half-cluster while
// ks=1 reads are in flight; lgkmcnt(0) before ks=1 half preserves the invariant
// "all own ds_reads complete before next s_barrier" (protects staged-buffer WAR).
// vmcnt ledger unchanged: stage A0(Q0),B0(Q1),B1(Q2),A1(Q3); vmcnt(4)+barrier at
// Q0,Q1,Q2 only.
__global__ __launch_bounds__(512, 2) void gemm1_8p_kernel(const unsigned short* __restrict__ A,
                                                          const unsigned short* __restrict__ Bt,
                                                          unsigned short* __restrict__ Cp) {
  __shared__ __align__(16) char lds[131072];   // A: [2][32768]; B: 65536 + [2][32768]
  int bid = blockIdx.x;
  int tile = (bid & 7) * 32 + (bid >> 3);      // bijective XCD swizzle (256 = 8*32)
  int bm = tile & 3;                           // 4 M-tiles (928 -> 1024)
  int bn = (tile >> 2) & 7;                    // 8 N-tiles
  int s = tile >> 5;                           // 8 splits
  int nkt = (s < 7) ? 25 : 21;                 // 196 = 7*25 + 21 K-tiles
  long kb = (long)s * 1600;                    // split K base

  int t = threadIdx.x;
  int lane = t & 63, wv = t >> 6;
  int wr = (wv >> 2) & 1, wc = wv & 3;
  int fr = lane & 15, fq = lane >> 4;
  int srow = t >> 3, sch = t & 7;

  f32x4 acc[8][4];
#pragma unroll
  for (int m = 0; m < 8; ++m)
#pragma unroll
    for (int n = 0; n < 4; ++n) acc[m][n] = (f32x4){0.f, 0.f, 0.f, 0.f};

#define STG(isB, h, ktl, bufs) do {                                            \
    _Pragma("unroll")                                                          \
    for (int j = 0; j < 2; ++j) {                                              \
      int rl = (h) * 128 + srow + j * 64;                                      \
      long grow = (isB) ? (long)(bn * 256 + rl) : (long)min(bm * 256 + rl, MROWS - 1); \
      const unsigned short* sp = ((isB) ? Bt : A) + grow * DDIM + kb + (ktl) * 64 \
                                 + ((sch ^ (rl & 7)) * 8);                     \
      gload_lds16(sp, lds + ((isB) ? 65536 : 0) + (bufs) * 32768               \
                          + (h) * 16384 + j * 8192 + t * 16);                  \
    }                                                                          \
  } while (0)

#define LDA_KS(dst, mh, bufc, ks) do {                                         \
    _Pragma("unroll")                                                          \
    for (int mi = 0; mi < 4; ++mi) {                                           \
      int row = (mh) * 128 + wr * 64 + mi * 16 + fr;                           \
      dst[mi][ks] = *(const bf16x8*)(lds + (bufc) * 32768 + row * 128          \
                                     + (((ks) * 64 + fq * 16) ^ ((row & 7) << 4))); \
    }                                                                          \
  } while (0)

#define LDB_KS(dst, nh, bufc, ks) do {                                         \
    _Pragma("unroll")                                                          \
    for (int ni = 0; ni < 2; ++ni) {                                           \
      int row = (nh) * 128 + wc * 32 + ni * 16 + fr;                           \
      dst[ni][ks] = *(const bf16x8*)(lds + 65536 + (bufc) * 32768 + row * 128  \
                                     + (((ks) * 64 + fq * 16) ^ ((row & 7) << 4))); \
    }                                                                          \
  } while (0)

#define WAITBAR() do {                                                         \
    asm volatile("s_waitcnt vmcnt(4)" ::: "memory");                           \
    __builtin_amdgcn_sched_barrier(0);                                         \
    __builtin_amdgcn_s_barrier();                                              \
    __builtin_amdgcn_sched_barrier(0);                                         \
  } while (0)

#define WAITL0() do {                                                          \
    asm volatile("s_waitcnt lgkmcnt(0)" ::: "memory");                         \
    __builtin_amdgcn_sched_barrier(0);                                         \
  } while (0)

#define WAITL(n) do {                                                          \
    asm volatile("s_waitcnt lgkmcnt(" #n ")" ::: "memory");                    \
    __builtin_amdgcn_sched_barrier(0);                                         \
  } while (0)

#define MFMA_H(af, bfv, mh, nh, ks) do {                                       \
    _Pragma("unroll")                                                          \
    for (int mi = 0; mi < 4; ++mi)                                             \
      _Pragma("unroll")                                                        \
      for (int ni = 0; ni < 2; ++ni)                                           \
        acc[(mh) * 4 + mi][(nh) * 2 + ni] = __builtin_amdgcn_mfma_f32_16x16x32_bf16( \
            af[mi][ks], bfv[ni][ks], acc[(mh) * 4 + mi][(nh) * 2 + ni], 0, 0, 0); \
  } while (0)

  // prologue: stage kt0 -> buf0 in consumption order A0,B0,B1,A1 (8 loads)
  STG(0, 0, 0, 0);
  STG(1, 0, 0, 0);
  STG(1, 1, 0, 0);
  STG(0, 1, 0, 0);

  bf16x8 af[4][2], bfv0[2][2], bfv1[2][2];
  for (int H = 0; H < nkt; ++H) {
    int bufc = H & 1, bufs = bufc ^ 1;
    int ktn = min(H + 1, nkt - 1);             // ghost-clamped next K-tile

    // Q0 (mh=0, nh=0): 12 reads ks-major; MFMA ks0 overlaps ks1 reads; stage A0
    WAITBAR();
    LDA_KS(af, 0, bufc, 0);
    LDB_KS(bfv0, 0, bufc, 0);
    LDA_KS(af, 0, bufc, 1);
    LDB_KS(bfv0, 0, bufc, 1);
    STG(0, 0, ktn, bufs);
    WAITL(6);
    __builtin_amdgcn_s_setprio(1);
    MFMA_H(af, bfv0, 0, 0, 0);
    WAITL0();
    MFMA_H(af, bfv0, 0, 0, 1);
    __builtin_amdgcn_s_setprio(0);
    __builtin_amdgcn_sched_barrier(0);

    // Q1 (mh=0, nh=1): 4 reads (B1), A cached; stage B0
    WAITBAR();
    LDB_KS(bfv1, 1, bufc, 0);
    LDB_KS(bfv1, 1, bufc, 1);
    STG(1, 0, ktn, bufs);
    WAITL(2);
    __builtin_amdgcn_s_setprio(1);
    MFMA_H(af, bfv1, 0, 1, 0);
    WAITL0();
    MFMA_H(af, bfv1, 0, 1, 1);
    __builtin_amdgcn_s_setprio(0);
    __builtin_amdgcn_sched_barrier(0);

    // Q2 (mh=1, nh=1): 8 reads (A1), B1 cached; stage B1
    WAITBAR();
    LDA_KS(af, 1, bufc, 0);
    LDA_KS(af, 1, bufc, 1);
    STG(1, 1, ktn, bufs);
    WAITL(4);
    __builtin_amdgcn_s_setprio(1);
    MFMA_H(af, bfv1, 1, 1, 0);
    WAITL0();
    MFMA_H(af, bfv1, 1, 1, 1);
    __builtin_amdgcn_s_setprio(0);
    __builtin_amdgcn_sched_barrier(0);

    // Q3 (mh=1, nh=0): everything cached; stage A1; no wait/barrier
    STG(0, 1, ktn, bufs);
    __builtin_amdgcn_s_setprio(1);
    MFMA_H(af, bfv0, 1, 0, 0);
    MFMA_H(af, bfv0, 1, 0, 1);
    __builtin_amdgcn_s_setprio(0);
    __builtin_amdgcn_sched_barrier(0);
  }
#undef STG
#undef LDA_KS
#undef LDB_KS
#undef WAITBAR
#undef WAITL0
#undef WAITL
#undef MFMA_H
  asm volatile("s_waitcnt vmcnt(0) lgkmcnt(0)" ::: "memory");

  unsigned short* Cb = Cp + (long)s * MROWS * N1DIM;
#pragma unroll
  for (int m = 0; m < 8; ++m)
#pragma unroll
    for (int n = 0; n < 4; ++n) {
      int col = bn * 256 + (n >> 1) * 128 + wc * 32 + (n & 1) * 16 + fr;
#pragma unroll
      for (int j = 0; j < 4; ++j) {
        int row = bm * 256 + (m >> 2) * 128 + wr * 64 + (m & 3) * 16 + fq * 4 + j;
        if (row < MROWS) Cb[(long)row * N1DIM + col] = f2bf(acc[m][n][j]);
      }
    }
}

// ---------------- 4b. GEMM2: 128x128 counted-vmcnt split-K, bf16 partials out ----
__global__ __launch_bounds__(256, 2) void gemm_sk_kernel(const unsigned short* __restrict__ A,
                                                         const unsigned short* __restrict__ Bt,
                                                         unsigned short* __restrict__ Cp,
                                                         int M, int N, int K, int kchunk,
                                                         int gy, int q) {
  __shared__ unsigned short As[2 * 128 * 64];
  __shared__ unsigned short Bs[2 * 128 * 64];
  int bid = blockIdx.x;
  int tile = (bid & 7) * q + (bid >> 3);
  int bm = tile & 7;
  int rest = tile >> 3;
  int bn = rest % gy;
  int s = rest / gy;

  int t = threadIdx.x;
  int lane = t & 63, wv = t >> 6;
  int wr = wv >> 1, wc = wv & 1;
  int fr = lane & 15, fq = lane >> 4;

  f32x4 acc[4][4];
#pragma unroll
  for (int m = 0; m < 4; ++m)
#pragma unroll
    for (int n = 0; n < 4; ++n) acc[m][n] = (f32x4){0.f, 0.f, 0.f, 0.f};

  int srow = t >> 3;
  int scol = t & 7;
  int k_begin = s * kchunk;
  int k_end = min(k_begin + kchunk, K);
  int nkt = (k_end - k_begin) >> 6;

  int garow[4], gbrow[4], schunk[4];
#pragma unroll
  for (int i = 0; i < 4; ++i) {
    int row = srow + i * 32;
    schunk[i] = (scol ^ (row & 7)) * 8;
    garow[i] = min(bm * 128 + row, M - 1);
    gbrow[i] = bn * 128 + row;
  }

#define GSTAGE(buf, kt_) do {                                                  \
    int k0_ = k_begin + (kt_) * 64;                                            \
    _Pragma("unroll")                                                          \
    for (int i = 0; i < 4; ++i)                                                \
      gload_lds16(A + (long)garow[i] * K + k0_ + schunk[i],                    \
                  (char*)As + (buf) * 16384 + t * 16 + i * 4096);              \
    _Pragma("unroll")                                                          \
    for (int i = 0; i < 4; ++i)                                                \
      gload_lds16(Bt + (long)gbrow[i] * K + k0_ + schunk[i],                   \
                  (char*)Bs + (buf) * 16384 + t * 16 + i * 4096);              \
  } while (0)

  GSTAGE(0, 0);
  GSTAGE(1, min(1, nkt - 1));

  for (int kt = 0; kt < nkt; ++kt) {
    int cur = kt & 1;
    asm volatile("s_waitcnt vmcnt(8)" ::: "memory");
    __builtin_amdgcn_sched_barrier(0);
    __builtin_amdgcn_s_barrier();
    __builtin_amdgcn_sched_barrier(0);

    const char* Ab = (const char*)As + cur * 16384;
    const char* Bb = (const char*)Bs + cur * 16384;
#pragma unroll
    for (int ks = 0; ks < 2; ++ks) {
      bf16x8 af[4], bfv2[4];
#pragma unroll
      for (int m = 0; m < 4; ++m) {
        int row = wr * 64 + m * 16 + fr;
        int bc = (ks * 64 + fq * 16) ^ ((row & 7) << 4);
        af[m] = *(const bf16x8*)(Ab + row * 128 + bc);
      }
#pragma unroll
      for (int n = 0; n < 4; ++n) {
        int row = wc * 64 + n * 16 + fr;
        int bc = (ks * 64 + fq * 16) ^ ((row & 7) << 4);
        bfv2[n] = *(const bf16x8*)(Bb + row * 128 + bc);
      }
#pragma unroll
      for (int m = 0; m < 4; ++m)
#pragma unroll
        for (int n = 0; n < 4; ++n)
          acc[m][n] = __builtin_amdgcn_mfma_f32_16x16x32_bf16(af[m], bfv2[n], acc[m][n], 0, 0, 0);
    }

    __builtin_amdgcn_sched_barrier(0);
    __builtin_amdgcn_s_barrier();
    __builtin_amdgcn_sched_barrier(0);
    GSTAGE(cur, min(kt + 2, nkt - 1));
  }
#undef GSTAGE

  unsigned short* Cb = Cp + (long)s * M * N;
#pragma unroll
  for (int m = 0; m < 4; ++m)
#pragma unroll
    for (int n = 0; n < 4; ++n) {
      int col = bn * 128 + wc * 64 + n * 16 + fr;
#pragma unroll
      for (int j = 0; j < 4; ++j) {
        int row = bm * 128 + wr * 64 + m * 16 + fq * 4 + j;
        if (row < M) Cb[(long)row * N + col] = f2bf(acc[m][n][j]);
      }
    }
}

// ---------------- block reduce helper ----------------
static __device__ __forceinline__ void block_reduce2(float& a, float& b, float* sm) {
#pragma unroll
  for (int off = 32; off > 0; off >>= 1) {
    a += __shfl_down(a, off);
    b += __shfl_down(b, off);
  }
  int lane = threadIdx.x & 63, wv = threadIdx.x >> 6;
  if (lane == 0) { sm[wv] = a; sm[wv + 4] = b; }
  __syncthreads();
  a = sm[0] + sm[1] + sm[2] + sm[3];
  b = sm[4] + sm[5] + sm[6] + sm[7];
}

// ---------------- 5. bf16-partial-sum + bias + LN + ReLU -> bf16 h ----------------
__global__ __launch_bounds__(256) void ln1_kernel(const unsigned short* __restrict__ X,
                                                  const float* __restrict__ b1,
                                                  const float* __restrict__ g1,
                                                  const float* __restrict__ be1,
                                                  unsigned short* __restrict__ H) {
  __shared__ float sm[8];
  int row = blockIdx.x, t = threadIdx.x;
  int j0 = t * 8;
  float x[8];
  float4 bA = *(const float4*)&b1[j0];
  float4 bB = *(const float4*)&b1[j0 + 4];
  x[0] = bA.x; x[1] = bA.y; x[2] = bA.z; x[3] = bA.w;
  x[4] = bB.x; x[5] = bB.y; x[6] = bB.z; x[7] = bB.w;
#pragma unroll
  for (int s = 0; s < S1; ++s) {
    ushort8v v = *(const ushort8v*)&X[((long)s * MROWS + row) * N1DIM + j0];
#pragma unroll
    for (int i = 0; i < 8; ++i) x[i] += bf2f(v[i]);
  }
  float sum = 0.f, sq = 0.f;
#pragma unroll
  for (int i = 0; i < 8; ++i) { sum += x[i]; sq += x[i] * x[i]; }
  block_reduce2(sum, sq, sm);
  float mu = sum * (1.f / N1DIM);
  float inv = rsqrtf(sq * (1.f / N1DIM) - mu * mu + 1e-5f);
  float4 gA = *(const float4*)&g1[j0];
  float4 gB = *(const float4*)&g1[j0 + 4];
  float4 eA = *(const float4*)&be1[j0];
  float4 eB = *(const float4*)&be1[j0 + 4];
  float g[8] = {gA.x, gA.y, gA.z, gA.w, gB.x, gB.y, gB.z, gB.w};
  float e[8] = {eA.x, eA.y, eA.z, eA.w, eB.x, eB.y, eB.z, eB.w};
  ushort8v o;
#pragma unroll
  for (int i = 0; i < 8; ++i)
    o[i] = f2bf(fmaxf((x[i] - mu) * inv * g[i] + e[i], 0.f));
  *(ushort8v*)&H[(long)row * N1DIM + j0] = o;
}

// ---------------- 6. bf16-partial-sum + bias + LN + missing-token -> out ----------------
__global__ __launch_bounds__(256) void ln2_kernel(const unsigned short* __restrict__ X,
                                                  const float* __restrict__ b2,
                                                  const float* __restrict__ g2,
                                                  const float* __restrict__ be2,
                                                  const float* __restrict__ miss,
                                                  const int* __restrict__ det,
                                                  float* __restrict__ out) {
  __shared__ float sm[8];
  int row = blockIdx.x, t = threadIdx.x;
  float x[3];
  float sum = 0.f, sq = 0.f;
#pragma unroll
  for (int i = 0; i < 3; ++i) {
    int j = t + i * 256;
    float v = b2[j];
#pragma unroll
    for (int s = 0; s < S2; ++s) v += bf2f(X[((long)s * MROWS + row) * FDIM + j]);
    x[i] = v;
    sum += v;
    sq += v * v;
  }
  block_reduce2(sum, sq, sm);
  float mu = sum * (1.f / FDIM);
  float inv = rsqrtf(sq * (1.f / FDIM) - mu * mu + 1e-5f);
  int dv = det[row];
#pragma unroll
  for (int i = 0; i < 3; ++i) {
    int j = t + i * 256;
    float y = (x[i] - mu) * inv * g2[j] + be2[j];
    out[(long)row * FDIM + j] = dv ? y : miss[j];
  }
}

extern "C" void kernel_launch(void* const* d_in, const int* in_sizes, int n_in,
                              void* d_out, int out_size, void* d_ws, size_t ws_size,
                              hipStream_t stream) {
  const float* fm     = (const float*)d_in[0];
  const float* boxes  = (const float*)d_in[1];
  const float* scores = (const float*)d_in[2];
  const int*   labels = (const int*)d_in[3];
  const float* w1     = (const float*)d_in[4];
  const float* b1     = (const float*)d_in[5];
  const float* g1     = (const float*)d_in[6];
  const float* be1    = (const float*)d_in[7];
  const float* w2     = (const float*)d_in[8];
  const float* b2     = (const float*)d_in[9];
  const float* g2     = (const float*)d_in[10];
  const float* be2    = (const float*)d_in[11];
  const float* miss   = (const float*)d_in[12];
  float* out = (float*)d_out;
  char* ws = (char*)d_ws;

  float* rois = (float*)(ws + OFF_ROIS);
  int* det = (int*)(ws + OFF_DET);
  unsigned short* Abf = (unsigned short*)(ws + OFF_A);
  unsigned short* fmT = (unsigned short*)(ws + OFF_FMT);
  unsigned short* w1t = (unsigned short*)(ws + OFF_W1T);
  unsigned short* w2t = (unsigned short*)(ws + OFF_W2T);
  unsigned short* Gp = (unsigned short*)(ws + OFF_GP);
  unsigned short* Hbf = (unsigned short*)(ws + OFF_H);

  hipLaunchKernelGGL(selfmt_kernel, dim3(8192 + 4), dim3(256), 0, stream,
                     fm, fmT, boxes, scores, labels, rois, det, out + (long)MROWS * FDIM);
  hipLaunchKernelGGL(roiwT_kernel,
                     dim3(MROWS + (DDIM / 64) * (N1DIM / 64) + (N1DIM / 64) * (FDIM / 64)),
                     dim3(256), 0, stream, fmT, rois, Abf, w1, w1t, w2, w2t);
  // GEMM1: counted-vmcnt 256x256, grid 4x8x8 = 256 blocks, 512 threads
  hipLaunchKernelGGL(gemm1_8p_kernel, dim3(256), dim3(512), 0, stream, Abf, w1t, Gp);
  hipLaunchKernelGGL(ln1_kernel, dim3(MROWS), dim3(256), 0, stream, Gp, b1, g1, be1, Hbf);
  // W1T dead (H aliases it); Gp reused for GEMM2 partials
  {
    int nkb = N1DIM / 64;
    int kc = ((nkb + S2 - 1) / S2) * 64;              // 256
    int gy = FDIM / 128, nwg = 8 * gy * S2;           // 384
    hipLaunchKernelGGL(gemm_sk_kernel, dim3(nwg), dim3(256), 0, stream,
                       Hbf, w2t, Gp, MROWS, FDIM, N1DIM, kc, gy, nwg / 8);
  }
  hipLaunchKernelGGL(ln2_kernel, dim3(MROWS), dim3(256), 0, stream,
                     Gp, b2, g2, be2, miss, det, out);
}

// Round 16
// 163.231 us; speedup vs baseline: 1.0235x; 1.0235x over previous
//
#include <hip/hip_runtime.h>

typedef __bf16 bf16x8 __attribute__((ext_vector_type(8)));
typedef float f32x4 __attribute__((ext_vector_type(4)));
typedef unsigned short ushort8v __attribute__((ext_vector_type(8)));
typedef unsigned short ushort4v __attribute__((ext_vector_type(4)));

#define BATCH 32
#define NBOX 40
#define CCH 256
#define HF 64
#define WF 64
#define RREG 29
#define OUTP 7
#define MROWS 928           // BATCH*RREG
#define DDIM 12544          // CCH*7*7
#define N1DIM 2048
#define FDIM 768
#define PDIM 4096           // HF*WF
#define S1 8                // split-K GEMM1 (25/.../21 K-tiles per split)
#define S2 8                // split-K factor GEMM2

// ---- workspace layout (bytes). Gp is bf16 [S][rows][cols]. ----
static constexpr size_t OFF_ROIS = 0;                                   // 928*4 f32
static constexpr size_t OFF_DET  = 16384;                               // 928 i32
static constexpr size_t OFF_A    = 32768;                               // bf16 [928][12544]
static constexpr size_t OFF_W1T  = OFF_A   + (size_t)MROWS * DDIM * 2;  // bf16 [2048][12544]
static constexpr size_t OFF_W2T  = OFF_W1T + (size_t)DDIM * N1DIM * 2;  // bf16 [768][2048]
static constexpr size_t OFF_GP   = OFF_W2T + (size_t)N1DIM * FDIM * 2;  // bf16 [S1][928][2048] / [S2][928][768]
static constexpr size_t OFF_FMT  = OFF_GP  + (size_t)S1 * MROWS * N1DIM * 2; // bf16 [32][4096][256]
static constexpr size_t OFF_H    = OFF_W1T;                             // bf16 [928][2048] (W1T dead after gemm1)

static __device__ __forceinline__ unsigned short f2bf(float f) {
  __bf16 h = (__bf16)f;
  return __builtin_bit_cast(unsigned short, h);
}
static __device__ __forceinline__ float bf2f(unsigned short u) {
  unsigned int x = ((unsigned int)u) << 16;
  return __builtin_bit_cast(float, x);
}
static __device__ __forceinline__ void gload_lds16(const void* g, void* l) {
  __builtin_amdgcn_global_load_lds((const __attribute__((address_space(1))) void*)g,
                                   (__attribute__((address_space(3))) void*)l, 16, 0, 0);
}

// ---------------- 1. select (4 blocks) + fmt NCHW f32 -> NHWC bf16 (8192 blocks) ----
__global__ __launch_bounds__(256) void selfmt_kernel(const float* __restrict__ in,
                                                     unsigned short* __restrict__ out,
                                                     const float* __restrict__ boxes,
                                                     const float* __restrict__ scores,
                                                     const int* __restrict__ labels,
                                                     float* __restrict__ rois,
                                                     int* __restrict__ det,
                                                     float* __restrict__ out_det) {
  __shared__ float tile[64][65];
  int bid = blockIdx.x;
  int t = threadIdx.x;
  if (bid >= PDIM / 64 * (CCH / 64) * BATCH) {   // ---- select part (4 trailing blocks)
    int tid = (bid - PDIM / 64 * (CCH / 64) * BATCH) * 256 + t;
    if (tid >= MROWS) return;
    int b = tid / RREG, r = tid % RREG;
    float bestS = -1.0f;
    int bestN = 0;
    int found = 0;
    for (int n = 0; n < NBOX; ++n) {
      int lab = labels[b * NBOX + n];
      int ri = min(max(lab, 1), RREG) - 1;
      if (ri == r) {
        found = 1;
        float s = scores[b * NBOX + n];
        if (s > bestS) { bestS = s; bestN = n; }
      }
    }
    const float scale = 0.0625f;
    float4 bx = *(const float4*)&boxes[(b * NBOX + bestN) * 4];
    rois[tid * 4 + 0] = bx.x * scale;
    rois[tid * 4 + 1] = bx.y * scale;
    rois[tid * 4 + 2] = bx.z * scale;
    rois[tid * 4 + 3] = bx.w * scale;
    det[tid] = found;
    out_det[tid] = found ? 1.0f : 0.0f;
    return;
  }
  // ---- fmt part
  int p0 = (bid & 63) * 64, c0 = ((bid >> 6) & 3) * 64, b = bid >> 8;
  int tx = t & 15, ty = t >> 4;
#pragma unroll
  for (int q = 0; q < 4; ++q) {
    int r = ty + q * 16;
    float4 v = *(const float4*)&in[((long)b * CCH + c0 + r) * PDIM + p0 + tx * 4];
    tile[r][tx * 4 + 0] = v.x;
    tile[r][tx * 4 + 1] = v.y;
    tile[r][tx * 4 + 2] = v.z;
    tile[r][tx * 4 + 3] = v.w;
  }
  __syncthreads();
#pragma unroll
  for (int q = 0; q < 4; ++q) {
    int r = ty + q * 16;
    ushort4v o;
    o[0] = f2bf(tile[tx * 4 + 0][r]);
    o[1] = f2bf(tile[tx * 4 + 1][r]);
    o[2] = f2bf(tile[tx * 4 + 2][r]);
    o[3] = f2bf(tile[tx * 4 + 3][r]);
    *(ushort4v*)&out[((long)b * PDIM + p0 + r) * CCH + c0 + tx * 4] = o;
  }
}

// ---------------- 2. merged roi-align + weight transpose ----------------
__global__ __launch_bounds__(256) void roiwT_kernel(const unsigned short* __restrict__ fmT,
                                                    const float* __restrict__ rois,
                                                    unsigned short* __restrict__ A,
                                                    const float* __restrict__ w1,
                                                    unsigned short* __restrict__ w1t,
                                                    const float* __restrict__ w2,
                                                    unsigned short* __restrict__ w2t) {
  __shared__ __align__(16) char lds[31360];
  int bid = blockIdx.x;
  int t = threadIdx.x;

  if (bid < MROWS) {
    // ---------------- roi part ----------------
    unsigned short* Arow = (unsigned short*)lds;            // [12544]
    int (*sidx)[4] = (int(*)[4])(lds + 25088);              // [196][4]
    float (*swt)[4] = (float(*)[4])(lds + 28224);           // [196][4]
    int roi = bid;
    float rx1 = rois[roi * 4 + 0], ry1 = rois[roi * 4 + 1];
    float rx2 = rois[roi * 4 + 2], ry2 = rois[roi * 4 + 3];
    float roiw = fmaxf(rx2 - rx1, 1.f), roih = fmaxf(ry2 - ry1, 1.f);
    float bw = roiw * (1.f / OUTP), bh = roih * (1.f / OUTP);
    if (t < 196) {
      int oy = t / 28, rem = t % 28, ox = rem / 4, s = rem % 4, sy = s >> 1, sx = s & 1;
      float y = ry1 + ((float)oy + ((float)sy + 0.5f) * 0.5f) * bh;
      float x = rx1 + ((float)ox + ((float)sx + 0.5f) * 0.5f) * bw;
      bool valid = (y >= -1.f) && (y <= 64.f) && (x >= -1.f) && (x <= 64.f);
      float yc = fminf(fmaxf(y, 0.f), 63.f);
      float xc = fminf(fmaxf(x, 0.f), 63.f);
      int y0 = (int)floorf(yc), x0 = (int)floorf(xc);
      int y1i = min(y0 + 1, 63), x1i = min(x0 + 1, 63);
      float ly = yc - (float)y0, lx = xc - (float)x0;
      float hy = 1.f - ly, hx = 1.f - lx;
      float m = valid ? 1.f : 0.f;
      swt[t][0] = hy * hx * m;
      swt[t][1] = hy * lx * m;
      swt[t][2] = ly * hx * m;
      swt[t][3] = ly * lx * m;
      sidx[t][0] = (y0 * 64 + x0) * CCH;
      sidx[t][1] = (y0 * 64 + x1i) * CCH;
      sidx[t][2] = (y1i * 64 + x0) * CCH;
      sidx[t][3] = (y1i * 64 + x1i) * CCH;
    }
    __syncthreads();
    int b = roi / RREG;
    int cg = t & 63;
    int sub = t >> 6;
    int start = sub * 12 + min(sub, 1);
    int cnt = sub == 0 ? 13 : 12;
    const unsigned short* base = fmT + (long)b * PDIM * CCH + cg * 4;
    for (int bi = 0; bi < cnt; ++bi) {
      int bin = start + bi;
      float a0 = 0.f, a1 = 0.f, a2 = 0.f, a3 = 0.f;
#pragma unroll
      for (int s = 0; s < 4; ++s) {
        int sid = bin * 4 + s;
#pragma unroll
        for (int tp = 0; tp < 4; ++tp) {
          float w = swt[sid][tp];
          ushort4v v = *(const ushort4v*)(base + sidx[sid][tp]);
          a0 += w * bf2f(v[0]);
          a1 += w * bf2f(v[1]);
          a2 += w * bf2f(v[2]);
          a3 += w * bf2f(v[3]);
        }
      }
      Arow[(cg * 4 + 0) * 49 + bin] = f2bf(a0 * 0.25f);
      Arow[(cg * 4 + 1) * 49 + bin] = f2bf(a1 * 0.25f);
      Arow[(cg * 4 + 2) * 49 + bin] = f2bf(a2 * 0.25f);
      Arow[(cg * 4 + 3) * 49 + bin] = f2bf(a3 * 0.25f);
    }
    __syncthreads();
    const ushort8v* src = (const ushort8v*)Arow;
    ushort8v* dst = (ushort8v*)(A + (long)roi * DDIM);
    for (int i = t; i < DDIM / 8; i += 256) dst[i] = src[i];
    return;
  }

  // ---------------- wT part ----------------
  float (*tile)[65] = (float(*)[65])lds;
  int wb = bid - MROWS;
  const float* in;
  unsigned short* out;
  int K, N, k0, n0;
  if (wb < (DDIM / 64) * (N1DIM / 64)) {
    in = w1; out = w1t; K = DDIM; N = N1DIM;
    k0 = (wb % (DDIM / 64)) * 64;
    n0 = (wb / (DDIM / 64)) * 64;
  } else {
    int r = wb - (DDIM / 64) * (N1DIM / 64);
    in = w2; out = w2t; K = N1DIM; N = FDIM;
    k0 = (r % (N1DIM / 64)) * 64;
    n0 = (r / (N1DIM / 64)) * 64;
  }
  int tx = t & 15, ty = t >> 4;
#pragma unroll
  for (int p = 0; p < 4; ++p) {
    int r = ty + p * 16;
    float4 v = *(const float4*)&in[(long)(k0 + r) * N + n0 + tx * 4];
    tile[r][tx * 4 + 0] = v.x;
    tile[r][tx * 4 + 1] = v.y;
    tile[r][tx * 4 + 2] = v.z;
    tile[r][tx * 4 + 3] = v.w;
  }
  __syncthreads();
#pragma unroll
  for (int p = 0; p < 4; ++p) {
    int r = ty + p * 16;
    ushort4v o;
    o[0] = f2bf(tile[tx * 4 + 0][r]);
    o[1] = f2bf(tile[tx * 4 + 1][r]);
    o[2] = f2bf(tile[tx * 4 + 2][r]);
    o[3] = f2bf(tile[tx * 4 + 3][r]);
    *(ushort4v*)&out[(long)(n0 + r) * K + k0 + tx * 4] = o;
  }
}

// ---------------- 4a. GEMM1: 256x256 8-wave counted-vmcnt, snake-order quadrants ----
// (R14 proven version.) Snake order (0,0)->(0,1)->(1,1)->(1,0); A loaded once per
// mh, B-halves cached in VGPRs -> 24 ds_read_b128/wave/K-tile. Stage order
// A0(Q0),B0(Q1),B1(Q2),A1(Q3); first-use Q0:A0+B0, Q1:B1, Q2:A1, Q3:none ->
// vmcnt(4)+barrier at Q0,Q1,Q2 only.
__global__ __launch_bounds__(512, 2) void gemm1_8p_kernel(const unsigned short* __restrict__ A,
                                                          const unsigned short* __restrict__ Bt,
                                                          unsigned short* __restrict__ Cp) {
  __shared__ __align__(16) char lds[131072];   // A: [2][32768]; B: 65536 + [2][32768]
  int bid = blockIdx.x;
  int tile = (bid & 7) * 32 + (bid >> 3);      // bijective XCD swizzle (256 = 8*32)
  int bm = tile & 3;                           // 4 M-tiles (928 -> 1024)
  int bn = (tile >> 2) & 7;                    // 8 N-tiles
  int s = tile >> 5;                           // 8 splits
  int nkt = (s < 7) ? 25 : 21;                 // 196 = 7*25 + 21 K-tiles
  long kb = (long)s * 1600;                    // split K base

  int t = threadIdx.x;
  int lane = t & 63, wv = t >> 6;
  int wr = (wv >> 2) & 1, wc = wv & 3;
  int fr = lane & 15, fq = lane >> 4;
  int srow = t >> 3, sch = t & 7;

  f32x4 acc[8][4];
#pragma unroll
  for (int m = 0; m < 8; ++m)
#pragma unroll
    for (int n = 0; n < 4; ++n) acc[m][n] = (f32x4){0.f, 0.f, 0.f, 0.f};

#define STG(isB, h, ktl, bufs) do {                                            \
    _Pragma("unroll")                                                          \
    for (int j = 0; j < 2; ++j) {                                              \
      int rl = (h) * 128 + srow + j * 64;                                      \
      long grow = (isB) ? (long)(bn * 256 + rl) : (long)min(bm * 256 + rl, MROWS - 1); \
      const unsigned short* sp = ((isB) ? Bt : A) + grow * DDIM + kb + (ktl) * 64 \
                                 + ((sch ^ (rl & 7)) * 8);                     \
      gload_lds16(sp, lds + ((isB) ? 65536 : 0) + (bufs) * 32768               \
                          + (h) * 16384 + j * 8192 + t * 16);                  \
    }                                                                          \
  } while (0)

#define LDA(dst, mh, bufc) do {                                                \
    _Pragma("unroll")                                                          \
    for (int mi = 0; mi < 4; ++mi) {                                           \
      int row = (mh) * 128 + wr * 64 + mi * 16 + fr;                           \
      _Pragma("unroll")                                                        \
      for (int ks = 0; ks < 2; ++ks)                                           \
        dst[mi][ks] = *(const bf16x8*)(lds + (bufc) * 32768 + row * 128        \
                                       + ((ks * 64 + fq * 16) ^ ((row & 7) << 4))); \
    }                                                                          \
  } while (0)

#define LDB(dst, nh, bufc) do {                                                \
    _Pragma("unroll")                                                          \
    for (int ni = 0; ni < 2; ++ni) {                                           \
      int row = (nh) * 128 + wc * 32 + ni * 16 + fr;                           \
      _Pragma("unroll")                                                        \
      for (int ks = 0; ks < 2; ++ks)                                           \
        dst[ni][ks] = *(const bf16x8*)(lds + 65536 + (bufc) * 32768 + row * 128 \
                                       + ((ks * 64 + fq * 16) ^ ((row & 7) << 4))); \
    }                                                                          \
  } while (0)

#define WAITBAR() do {                                                         \
    asm volatile("s_waitcnt vmcnt(4)" ::: "memory");                           \
    __builtin_amdgcn_sched_barrier(0);                                         \
    __builtin_amdgcn_s_barrier();                                              \
    __builtin_amdgcn_sched_barrier(0);                                         \
  } while (0)

#define MFMA8(af, bfv, mh, nh) do {                                            \
    asm volatile("s_waitcnt lgkmcnt(0)" ::: "memory");                         \
    __builtin_amdgcn_sched_barrier(0);                                         \
    __builtin_amdgcn_s_setprio(1);                                             \
    _Pragma("unroll")                                                          \
    for (int mi = 0; mi < 4; ++mi)                                             \
      _Pragma("unroll")                                                        \
      for (int ni = 0; ni < 2; ++ni)                                           \
        _Pragma("unroll")                                                      \
        for (int ks = 0; ks < 2; ++ks)                                         \
          acc[(mh) * 4 + mi][(nh) * 2 + ni] = __builtin_amdgcn_mfma_f32_16x16x32_bf16( \
              af[mi][ks], bfv[ni][ks], acc[(mh) * 4 + mi][(nh) * 2 + ni], 0, 0, 0); \
    __builtin_amdgcn_s_setprio(0);                                             \
    __builtin_amdgcn_sched_barrier(0);                                         \
  } while (0)

  // prologue: stage kt0 -> buf0 in consumption order A0,B0,B1,A1 (8 loads)
  STG(0, 0, 0, 0);
  STG(1, 0, 0, 0);
  STG(1, 1, 0, 0);
  STG(0, 1, 0, 0);

  bf16x8 af[4][2], bfv0[2][2], bfv1[2][2];
  for (int H = 0; H < nkt; ++H) {
    int bufc = H & 1, bufs = bufc ^ 1;
    int ktn = min(H + 1, nkt - 1);             // ghost-clamped next K-tile

    // Q0 (mh=0, nh=0): load A-half0 + B-half0; stage A0
    WAITBAR();
    LDA(af, 0, bufc);
    LDB(bfv0, 0, bufc);
    STG(0, 0, ktn, bufs);
    MFMA8(af, bfv0, 0, 0);

    // Q1 (mh=0, nh=1): load B-half1 (A cached); stage B0
    WAITBAR();
    LDB(bfv1, 1, bufc);
    STG(1, 0, ktn, bufs);
    MFMA8(af, bfv1, 0, 1);

    // Q2 (mh=1, nh=1): load A-half1 (B1 cached); stage B1
    WAITBAR();
    LDA(af, 1, bufc);
    STG(1, 1, ktn, bufs);
    MFMA8(af, bfv1, 1, 1);

    // Q3 (mh=1, nh=0): everything cached; stage A1; no wait/barrier
    STG(0, 1, ktn, bufs);
    MFMA8(af, bfv0, 1, 0);
  }
#undef STG
#undef LDA
#undef LDB
#undef WAITBAR
#undef MFMA8
  asm volatile("s_waitcnt vmcnt(0) lgkmcnt(0)" ::: "memory");

  unsigned short* Cb = Cp + (long)s * MROWS * N1DIM;
#pragma unroll
  for (int m = 0; m < 8; ++m)
#pragma unroll
    for (int n = 0; n < 4; ++n) {
      int col = bn * 256 + (n >> 1) * 128 + wc * 32 + (n & 1) * 16 + fr;
#pragma unroll
      for (int j = 0; j < 4; ++j) {
        int row = bm * 256 + (m >> 2) * 128 + wr * 64 + (m & 3) * 16 + fq * 4 + j;
        if (row < MROWS) Cb[(long)row * N1DIM + col] = f2bf(acc[m][n][j]);
      }
    }
}

// ---------------- 4b. GEMM2: 128x128 counted-vmcnt split-K, bf16 partials out ----
__global__ __launch_bounds__(256, 2) void gemm_sk_kernel(const unsigned short* __restrict__ A,
                                                         const unsigned short* __restrict__ Bt,
                                                         unsigned short* __restrict__ Cp,
                                                         int M, int N, int K, int kchunk,
                                                         int gy, int q) {
  __shared__ unsigned short As[2 * 128 * 64];
  __shared__ unsigned short Bs[2 * 128 * 64];
  int bid = blockIdx.x;
  int tile = (bid & 7) * q + (bid >> 3);
  int bm = tile & 7;
  int rest = tile >> 3;
  int bn = rest % gy;
  int s = rest / gy;

  int t = threadIdx.x;
  int lane = t & 63, wv = t >> 6;
  int wr = wv >> 1, wc = wv & 1;
  int fr = lane & 15, fq = lane >> 4;

  f32x4 acc[4][4];
#pragma unroll
  for (int m = 0; m < 4; ++m)
#pragma unroll
    for (int n = 0; n < 4; ++n) acc[m][n] = (f32x4){0.f, 0.f, 0.f, 0.f};

  int srow = t >> 3;
  int scol = t & 7;
  int k_begin = s * kchunk;
  int k_end = min(k_begin + kchunk, K);
  int nkt = (k_end - k_begin) >> 6;

  int garow[4], gbrow[4], schunk[4];
#pragma unroll
  for (int i = 0; i < 4; ++i) {
    int row = srow + i * 32;
    schunk[i] = (scol ^ (row & 7)) * 8;
    garow[i] = min(bm * 128 + row, M - 1);
    gbrow[i] = bn * 128 + row;
  }

#define GSTAGE(buf, kt_) do {                                                  \
    int k0_ = k_begin + (kt_) * 64;                                            \
    _Pragma("unroll")                                                          \
    for (int i = 0; i < 4; ++i)                                                \
      gload_lds16(A + (long)garow[i] * K + k0_ + schunk[i],                    \
                  (char*)As + (buf) * 16384 + t * 16 + i * 4096);              \
    _Pragma("unroll")                                                          \
    for (int i = 0; i < 4; ++i)                                                \
      gload_lds16(Bt + (long)gbrow[i] * K + k0_ + schunk[i],                   \
                  (char*)Bs + (buf) * 16384 + t * 16 + i * 4096);              \
  } while (0)

  GSTAGE(0, 0);
  GSTAGE(1, min(1, nkt - 1));

  for (int kt = 0; kt < nkt; ++kt) {
    int cur = kt & 1;
    asm volatile("s_waitcnt vmcnt(8)" ::: "memory");
    __builtin_amdgcn_sched_barrier(0);
    __builtin_amdgcn_s_barrier();
    __builtin_amdgcn_sched_barrier(0);

    const char* Ab = (const char*)As + cur * 16384;
    const char* Bb = (const char*)Bs + cur * 16384;
#pragma unroll
    for (int ks = 0; ks < 2; ++ks) {
      bf16x8 af[4], bfv2[4];
#pragma unroll
      for (int m = 0; m < 4; ++m) {
        int row = wr * 64 + m * 16 + fr;
        int bc = (ks * 64 + fq * 16) ^ ((row & 7) << 4);
        af[m] = *(const bf16x8*)(Ab + row * 128 + bc);
      }
#pragma unroll
      for (int n = 0; n < 4; ++n) {
        int row = wc * 64 + n * 16 + fr;
        int bc = (ks * 64 + fq * 16) ^ ((row & 7) << 4);
        bfv2[n] = *(const bf16x8*)(Bb + row * 128 + bc);
      }
#pragma unroll
      for (int m = 0; m < 4; ++m)
#pragma unroll
        for (int n = 0; n < 4; ++n)
          acc[m][n] = __builtin_amdgcn_mfma_f32_16x16x32_bf16(af[m], bfv2[n], acc[m][n], 0, 0, 0);
    }

    __builtin_amdgcn_sched_barrier(0);
    __builtin_amdgcn_s_barrier();
    __builtin_amdgcn_sched_barrier(0);
    GSTAGE(cur, min(kt + 2, nkt - 1));
  }
#undef GSTAGE

  unsigned short* Cb = Cp + (long)s * M * N;
#pragma unroll
  for (int m = 0; m < 4; ++m)
#pragma unroll
    for (int n = 0; n < 4; ++n) {
      int col = bn * 128 + wc * 64 + n * 16 + fr;
#pragma unroll
      for (int j = 0; j < 4; ++j) {
        int row = bm * 128 + wr * 64 + m * 16 + fq * 4 + j;
        if (row < M) Cb[(long)row * N + col] = f2bf(acc[m][n][j]);
      }
    }
}

// ---------------- block reduce helper ----------------
static __device__ __forceinline__ void block_reduce2(float& a, float& b, float* sm) {
#pragma unroll
  for (int off = 32; off > 0; off >>= 1) {
    a += __shfl_down(a, off);
    b += __shfl_down(b, off);
  }
  int lane = threadIdx.x & 63, wv = threadIdx.x >> 6;
  if (lane == 0) { sm[wv] = a; sm[wv + 4] = b; }
  __syncthreads();
  a = sm[0] + sm[1] + sm[2] + sm[3];
  b = sm[4] + sm[5] + sm[6] + sm[7];
}

// ---------------- 5. bf16-partial-sum + bias + LN + ReLU -> bf16 h ----------------
__global__ __launch_bounds__(256) void ln1_kernel(const unsigned short* __restrict__ X,
                                                  const float* __restrict__ b1,
                                                  const float* __restrict__ g1,
                                                  const float* __restrict__ be1,
                                                  unsigned short* __restrict__ H) {
  __shared__ float sm[8];
  int row = blockIdx.x, t = threadIdx.x;
  int j0 = t * 8;
  float x[8];
  float4 bA = *(const float4*)&b1[j0];
  float4 bB = *(const float4*)&b1[j0 + 4];
  x[0] = bA.x; x[1] = bA.y; x[2] = bA.z; x[3] = bA.w;
  x[4] = bB.x; x[5] = bB.y; x[6] = bB.z; x[7] = bB.w;
#pragma unroll
  for (int s = 0; s < S1; ++s) {
    ushort8v v = *(const ushort8v*)&X[((long)s * MROWS + row) * N1DIM + j0];
#pragma unroll
    for (int i = 0; i < 8; ++i) x[i] += bf2f(v[i]);
  }
  float sum = 0.f, sq = 0.f;
#pragma unroll
  for (int i = 0; i < 8; ++i) { sum += x[i]; sq += x[i] * x[i]; }
  block_reduce2(sum, sq, sm);
  float mu = sum * (1.f / N1DIM);
  float inv = rsqrtf(sq * (1.f / N1DIM) - mu * mu + 1e-5f);
  float4 gA = *(const float4*)&g1[j0];
  float4 gB = *(const float4*)&g1[j0 + 4];
  float4 eA = *(const float4*)&be1[j0];
  float4 eB = *(const float4*)&be1[j0 + 4];
  float g[8] = {gA.x, gA.y, gA.z, gA.w, gB.x, gB.y, gB.z, gB.w};
  float e[8] = {eA.x, eA.y, eA.z, eA.w, eB.x, eB.y, eB.z, eB.w};
  ushort8v o;
#pragma unroll
  for (int i = 0; i < 8; ++i)
    o[i] = f2bf(fmaxf((x[i] - mu) * inv * g[i] + e[i], 0.f));
  *(ushort8v*)&H[(long)row * N1DIM + j0] = o;
}

// ---------------- 6. bf16-partial-sum + bias + LN + missing-token -> out ----------------
__global__ __launch_bounds__(256) void ln2_kernel(const unsigned short* __restrict__ X,
                                                  const float* __restrict__ b2,
                                                  const float* __restrict__ g2,
                                                  const float* __restrict__ be2,
                                                  const float* __restrict__ miss,
                                                  const int* __restrict__ det,
                                                  float* __restrict__ out) {
  __shared__ float sm[8];
  int row = blockIdx.x, t = threadIdx.x;
  float x[3];
  float sum = 0.f, sq = 0.f;
#pragma unroll
  for (int i = 0; i < 3; ++i) {
    int j = t + i * 256;
    float v = b2[j];
#pragma unroll
    for (int s = 0; s < S2; ++s) v += bf2f(X[((long)s * MROWS + row) * FDIM + j]);
    x[i] = v;
    sum += v;
    sq += v * v;
  }
  block_reduce2(sum, sq, sm);
  float mu = sum * (1.f / FDIM);
  float inv = rsqrtf(sq * (1.f / FDIM) - mu * mu + 1e-5f);
  int dv = det[row];
#pragma unroll
  for (int i = 0; i < 3; ++i) {
    int j = t + i * 256;
    float y = (x[i] - mu) * inv * g2[j] + be2[j];
    out[(long)row * FDIM + j] = dv ? y : miss[j];
  }
}

extern "C" void kernel_launch(void* const* d_in, const int* in_sizes, int n_in,
                              void* d_out, int out_size, void* d_ws, size_t ws_size,
                              hipStream_t stream) {
  const float* fm     = (const float*)d_in[0];
  const float* boxes  = (const float*)d_in[1];
  const float* scores = (const float*)d_in[2];
  const int*   labels = (const int*)d_in[3];
  const float* w1     = (const float*)d_in[4];
  const float* b1     = (const float*)d_in[5];
  const float* g1     = (const float*)d_in[6];
  const float* be1    = (const float*)d_in[7];
  const float* w2     = (const float*)d_in[8];
  const float* b2     = (const float*)d_in[9];
  const float* g2     = (const float*)d_in[10];
  const float* be2    = (const float*)d_in[11];
  const float* miss   = (const float*)d_in[12];
  float* out = (float*)d_out;
  char* ws = (char*)d_ws;

  float* rois = (float*)(ws + OFF_ROIS);
  int* det = (int*)(ws + OFF_DET);
  unsigned short* Abf = (unsigned short*)(ws + OFF_A);
  unsigned short* fmT = (unsigned short*)(ws + OFF_FMT);
  unsigned short* w1t = (unsigned short*)(ws + OFF_W1T);
  unsigned short* w2t = (unsigned short*)(ws + OFF_W2T);
  unsigned short* Gp = (unsigned short*)(ws + OFF_GP);
  unsigned short* Hbf = (unsigned short*)(ws + OFF_H);

  hipLaunchKernelGGL(selfmt_kernel, dim3(8192 + 4), dim3(256), 0, stream,
                     fm, fmT, boxes, scores, labels, rois, det, out + (long)MROWS * FDIM);
  hipLaunchKernelGGL(roiwT_kernel,
                     dim3(MROWS + (DDIM / 64) * (N1DIM / 64) + (N1DIM / 64) * (FDIM / 64)),
                     dim3(256), 0, stream, fmT, rois, Abf, w1, w1t, w2, w2t);
  // GEMM1: counted-vmcnt 256x256, grid 4x8x8 = 256 blocks, 512 threads
  hipLaunchKernelGGL(gemm1_8p_kernel, dim3(256), dim3(512), 0, stream, Abf, w1t, Gp);
  hipLaunchKernelGGL(ln1_kernel, dim3(MROWS), dim3(256), 0, stream, Gp, b1, g1, be1, Hbf);
  // W1T dead (H aliases it); Gp reused for GEMM2 partials
  {
    int nkb = N1DIM / 64;
    int kc = ((nkb + S2 - 1) / S2) * 64;              // 256
    int gy = FDIM / 128, nwg = 8 * gy * S2;           // 384
    hipLaunchKernelGGL(gemm_sk_kernel, dim3(nwg), dim3(256), 0, stream,
                       Hbf, w2t, Gp, MROWS, FDIM, N1DIM, kc, gy, nwg / 8);
  }
  hipLaunchKernelGGL(ln2_kernel, dim3(MROWS), dim3(256), 0, stream,
                     Gp, b2, g2, be2, miss, det, out);
}